// Round 9
// baseline (604.991 us; speedup 1.0000x reference)
//
#include <hip/hip_runtime.h>
#include <math.h>

typedef __bf16 bf16_t;
typedef __bf16 bf16x8 __attribute__((ext_vector_type(8)));
typedef float f32x4 __attribute__((ext_vector_type(4)));

#define NN 8192
#define L2E 1.44269504088896340736f
#define SMAX 45.0f                    // fixed softmax shift: s-SMAX in [-75,+15], all normal fp32
#define KSCALE 0.35355339059327373f   // 1/sqrt(8); applied to khs on both sides => kh·kh/8
#define ACCW 66                       // acc row stride: 64 O cols + 1 l col + pad

// ---------------------------------------------------------------------------
// Kernel 1: projections (verified R5-R8).
// ---------------------------------------------------------------------------
__global__ __launch_bounds__(256) void proj_kernel(
    const float* __restrict__ input,
    const float* __restrict__ kW,
    const float* __restrict__ vW,
    bf16_t* __restrict__ khs_hi,
    bf16_t* __restrict__ khs_lo,
    bf16_t* __restrict__ vhT)
{
    __shared__ __align__(16) bf16_t WkH[64][136];
    __shared__ __align__(16) bf16_t WkL[64][136];
    __shared__ __align__(16) bf16_t WvH[64][136];
    __shared__ __align__(16) bf16_t WvL[64][136];

    const int tid   = threadIdx.x;
    const int wv    = tid >> 6;
    const int lane  = tid & 63;
    const int l15   = lane & 15;
    const int quad  = lane >> 4;
    const int rbase = blockIdx.x * 64 + wv * 16;

    f32x4 kacc[4] = {};
    f32x4 vacc[4] = {};

    for (int kk = 0; kk < 4; ++kk) {
        __syncthreads();
        #pragma unroll
        for (int i = 0; i < 32; ++i) {
            int idx = tid + i * 256;
            int kl  = idx >> 6;
            int n   = idx & 63;
            float wk  = kW[(kk * 128 + kl) * 64 + n];
            float wv2 = vW[(kk * 128 + kl) * 64 + n];
            bf16_t kh = (bf16_t)wk;
            bf16_t vh = (bf16_t)wv2;
            WkH[n][kl] = kh;  WkL[n][kl] = (bf16_t)(wk - (float)kh);
            WvH[n][kl] = vh;  WvL[n][kl] = (bf16_t)(wv2 - (float)vh);
        }
        __syncthreads();

        #pragma unroll
        for (int kc = 0; kc < 4; ++kc) {
            const float* ap = &input[(size_t)(rbase + l15) * 512 + kk * 128 + kc * 32 + quad * 8];
            f32x4 a0 = *(const f32x4*)ap;
            f32x4 a1 = *(const f32x4*)(ap + 4);
            bf16x8 ah, al;
            #pragma unroll
            for (int j = 0; j < 4; ++j) {
                bf16_t h0 = (bf16_t)a0[j], h1 = (bf16_t)a1[j];
                ah[j]     = h0;  al[j]     = (bf16_t)(a0[j] - (float)h0);
                ah[4 + j] = h1;  al[4 + j] = (bf16_t)(a1[j] - (float)h1);
            }
            #pragma unroll
            for (int nb = 0; nb < 4; ++nb) {
                bf16x8 bkh = *(const bf16x8*)&WkH[nb * 16 + l15][kc * 32 + quad * 8];
                bf16x8 bkl = *(const bf16x8*)&WkL[nb * 16 + l15][kc * 32 + quad * 8];
                bf16x8 bvh = *(const bf16x8*)&WvH[nb * 16 + l15][kc * 32 + quad * 8];
                bf16x8 bvl = *(const bf16x8*)&WvL[nb * 16 + l15][kc * 32 + quad * 8];
                kacc[nb] = __builtin_amdgcn_mfma_f32_16x16x32_bf16(ah, bkh, kacc[nb], 0, 0, 0);
                kacc[nb] = __builtin_amdgcn_mfma_f32_16x16x32_bf16(al, bkh, kacc[nb], 0, 0, 0);
                kacc[nb] = __builtin_amdgcn_mfma_f32_16x16x32_bf16(ah, bkl, kacc[nb], 0, 0, 0);
                vacc[nb] = __builtin_amdgcn_mfma_f32_16x16x32_bf16(ah, bvh, vacc[nb], 0, 0, 0);
                vacc[nb] = __builtin_amdgcn_mfma_f32_16x16x32_bf16(al, bvh, vacc[nb], 0, 0, 0);
                vacc[nb] = __builtin_amdgcn_mfma_f32_16x16x32_bf16(ah, bvl, vacc[nb], 0, 0, 0);
            }
        }
    }

    #pragma unroll
    for (int nb = 0; nb < 4; ++nb) {
        const int dcol = nb * 16 + l15;
        #pragma unroll
        for (int r = 0; r < 4; ++r) {
            float v  = kacc[nb][r] * KSCALE;
            bf16_t h = (bf16_t)v;
            khs_hi[(size_t)(rbase + quad * 4 + r) * 64 + dcol] = h;
            khs_lo[(size_t)(rbase + quad * 4 + r) * 64 + dcol] = (bf16_t)(v - (float)h);
        }
        union { bf16_t b[4]; uint2 u; } pk;
        #pragma unroll
        for (int r = 0; r < 4; ++r) pk.b[r] = (bf16_t)vacc[nb][r];
        *(uint2*)&vhT[(size_t)dcol * NN + rbase + quad * 4] = pk.u;
    }
}

// ---------------------------------------------------------------------------
// Kernel 1b: bitpack adj (268 MB int32) -> mask (8 MB; bit i of word g = col
// g*64+i). One wave per row; pure sequential stream at HBM BW.
// ---------------------------------------------------------------------------
__global__ __launch_bounds__(256) void bitpack(
    const int* __restrict__ adj, unsigned long long* __restrict__ mask64)
{
    const int gw   = (blockIdx.x * 256 + threadIdx.x) >> 6;   // row 0..8191
    const int lane = threadIdx.x & 63;
    const int* rp  = adj + (size_t)gw * NN + lane;
    unsigned long long* mp = mask64 + (size_t)gw * 128;
    #pragma unroll 8
    for (int g = 0; g < 128; ++g) {
        int v = rp[(size_t)g * 64];
        unsigned long long b = __ballot(v > 0);
        if (lane == 0) mp[g] = b;
    }
}

__global__ void zero_acc(float* __restrict__ acc) {
    int i = blockIdx.x * blockDim.x + threadIdx.x;
    if (i < NN * ACCW) acc[i] = 0.f;
}

// ---------------------------------------------------------------------------
// Kernel 2: transpose-free fixed-max attention. grid 1024 = 512 row-blocks
// x 2 col halves; 8 waves/block; wave owns 512 cols = 16 iters of 32 keys.
// S^T = mfma(A=K-frags, B=Q-frags): C/D holds (key-slot m, query n=l15).
// Key slots permuted (slot m <-> key 8*(m>>2)+(m&3); tile1 +4) so the two
// exp'd C-tiles ARE the PV A-fragment (lane: query=l15, keys quad*8+j).
// No LDS, no fences, no barriers in the loop -> compiler pipelines freely.
// ---------------------------------------------------------------------------
__global__ __launch_bounds__(512, 4) void attn_kernel(
    const unsigned int* __restrict__ mask,   // [8192][256] words
    const bf16_t* __restrict__ khs_hi,
    const bf16_t* __restrict__ khs_lo,
    const bf16_t* __restrict__ vhT,          // [64][8192]
    float* __restrict__ acc)                 // [8192][ACCW]
{
    __shared__ __align__(16) float Msl[4 * 16 * 68];   // merge slabs only (epilogue)

    const int tid   = threadIdx.x;
    const int w     = tid >> 6;
    const int lane  = tid & 63;
    const int l15   = lane & 15;
    const int quad  = lane >> 4;
    const int rb    = blockIdx.x >> 1;
    const int ch    = blockIdx.x & 1;
    const int qbase = rb * 16;
    const int colstart = ch * 4096 + w * 512;

    // Q fragments (B-side now; layout n=l15=query, k=quad*8+j dims), hi + lo
    const bf16x8 qh0 = *(const bf16x8*)&khs_hi[(size_t)(qbase + l15) * 64 + quad * 8];
    const bf16x8 qh1 = *(const bf16x8*)&khs_hi[(size_t)(qbase + l15) * 64 + 32 + quad * 8];
    const bf16x8 ql0 = *(const bf16x8*)&khs_lo[(size_t)(qbase + l15) * 64 + quad * 8];
    const bf16x8 ql1 = *(const bf16x8*)&khs_lo[(size_t)(qbase + l15) * 64 + 32 + quad * 8];

    bf16x8 ones;
    #pragma unroll
    for (int j = 0; j < 8; ++j) ones[j] = (bf16_t)1.0f;

    // per-lane mask words for row qbase+l15 (4-way redundant across quads, L2)
    const uint4* mrow = (const uint4*)(mask + (size_t)(qbase + l15) * 256 + ch * 128 + w * 16);

    // permuted A-row base: tile0 slot l15 <-> key 8*(l15>>2) + (l15&3)
    const int kperm = ((l15 >> 2) << 3) | (l15 & 3);

    f32x4 o0 = {}, o1 = {}, o2 = {}, o3 = {}, o4 = {};

    for (int t0 = 0; t0 < 4; ++t0) {
        uint4 mw4 = mrow[t0];
        #pragma unroll
        for (int u = 0; u < 4; ++u) {
            const int t = t0 * 4 + u;
            const int colbase = colstart + t * 32;
            const unsigned int word = (&mw4.x)[u];

            // A-side K fragments, permuted rows (hi only)
            const bf16_t* kp0 = khs_hi + (size_t)(colbase + kperm) * 64 + quad * 8;
            const bf16_t* kp1 = kp0 + 4 * 64;
            bf16x8 a00 = *(const bf16x8*)(kp0);
            bf16x8 a01 = *(const bf16x8*)(kp0 + 32);
            bf16x8 a10 = *(const bf16x8*)(kp1);
            bf16x8 a11 = *(const bf16x8*)(kp1 + 32);

            // V B-fragments: B[n=dim g*16+l15][k=quad*8+j -> key colbase+quad*8+j]
            const bf16_t* vp = vhT + (size_t)l15 * NN + colbase + quad * 8;
            bf16x8 bv0 = *(const bf16x8*)(vp);
            bf16x8 bv1 = *(const bf16x8*)(vp + (size_t)16 * NN);
            bf16x8 bv2 = *(const bf16x8*)(vp + (size_t)32 * NN);
            bf16x8 bv3 = *(const bf16x8*)(vp + (size_t)48 * NN);

            // S^T tiles: D[m=key-slot][n=query]
            f32x4 zz = {};
            f32x4 c0 = __builtin_amdgcn_mfma_f32_16x16x32_bf16(a00, qh0, zz, 0, 0, 0);
            c0 = __builtin_amdgcn_mfma_f32_16x16x32_bf16(a01, qh1, c0, 0, 0, 0);
            c0 = __builtin_amdgcn_mfma_f32_16x16x32_bf16(a00, ql0, c0, 0, 0, 0);
            c0 = __builtin_amdgcn_mfma_f32_16x16x32_bf16(a01, ql1, c0, 0, 0, 0);
            f32x4 c1 = __builtin_amdgcn_mfma_f32_16x16x32_bf16(a10, qh0, zz, 0, 0, 0);
            c1 = __builtin_amdgcn_mfma_f32_16x16x32_bf16(a11, qh1, c1, 0, 0, 0);
            c1 = __builtin_amdgcn_mfma_f32_16x16x32_bf16(a10, ql0, c1, 0, 0, 0);
            c1 = __builtin_amdgcn_mfma_f32_16x16x32_bf16(a11, ql1, c1, 0, 0, 0);

            // p = maskbit ? exp(s - SMAX) : 0 ; c0[r] -> key 8*quad+r, c1[r] -> +4
            bf16x8 pa;
            #pragma unroll
            for (int r = 0; r < 4; ++r) {
                float p0 = ((word >> (8 * quad + r)) & 1u)
                             ? __builtin_amdgcn_exp2f((c0[r] - SMAX) * L2E) : 0.f;
                float p1 = ((word >> (8 * quad + 4 + r)) & 1u)
                             ? __builtin_amdgcn_exp2f((c1[r] - SMAX) * L2E) : 0.f;
                pa[r]     = (bf16_t)p0;
                pa[4 + r] = (bf16_t)p1;
            }

            // PV + l, all in registers
            o0 = __builtin_amdgcn_mfma_f32_16x16x32_bf16(pa, bv0, o0, 0, 0, 0);
            o1 = __builtin_amdgcn_mfma_f32_16x16x32_bf16(pa, bv1, o1, 0, 0, 0);
            o2 = __builtin_amdgcn_mfma_f32_16x16x32_bf16(pa, bv2, o2, 0, 0, 0);
            o3 = __builtin_amdgcn_mfma_f32_16x16x32_bf16(pa, bv3, o3, 0, 0, 0);
            o4 = __builtin_amdgcn_mfma_f32_16x16x32_bf16(pa, ones, o4, 0, 0, 0);
        }
    }

    // ---- sum-tree merge of the 8 waves (epilogue only) ----
    // O layout: row(query)=quad*4+r, col(dim)=l15 (+16g) — same as R8.
    float* M = Msl;
    #pragma unroll
    for (int s = 4; s >= 1; s >>= 1) {
        __syncthreads();
        if (w >= s && w < 2 * s) {
            float* base = M + (w - s) * 16 * 68;
            #pragma unroll
            for (int r = 0; r < 4; ++r) {
                const int row = quad * 4 + r;
                base[row * 68 + l15]      = o0[r];
                base[row * 68 + 16 + l15] = o1[r];
                base[row * 68 + 32 + l15] = o2[r];
                base[row * 68 + 48 + l15] = o3[r];
                if (l15 == 0) base[row * 68 + 64] = o4[r];
            }
        }
        __syncthreads();
        if (w < s) {
            float* base = M + w * 16 * 68;
            #pragma unroll
            for (int r = 0; r < 4; ++r) {
                const int row = quad * 4 + r;
                o0[r] += base[row * 68 + l15];
                o1[r] += base[row * 68 + 16 + l15];
                o2[r] += base[row * 68 + 32 + l15];
                o3[r] += base[row * 68 + 48 + l15];
                o4[r] += base[row * 68 + 64];
            }
        }
    }

    if (w == 0) {
        #pragma unroll
        for (int r = 0; r < 4; ++r) {
            const size_t row = (size_t)qbase + quad * 4 + r;
            atomicAdd(&acc[row * ACCW + l15],      o0[r]);
            atomicAdd(&acc[row * ACCW + 16 + l15], o1[r]);
            atomicAdd(&acc[row * ACCW + 32 + l15], o2[r]);
            atomicAdd(&acc[row * ACCW + 48 + l15], o3[r]);
            if (l15 == 0) atomicAdd(&acc[row * ACCW + 64], o4[r]);
        }
    }
}

__global__ void finalize(const float* __restrict__ acc, float* __restrict__ out) {
    int i = blockIdx.x * blockDim.x + threadIdx.x;
    int row = i >> 6, d = i & 63;
    float l = acc[(size_t)row * ACCW + 64];
    float v = acc[(size_t)row * ACCW + d] / (l > 0.f ? l : 1.f);
    out[i] = v > 0.f ? v : expm1f(v);
}

// ---------------------------------------------------------------------------
extern "C" void kernel_launch(void* const* d_in, const int* in_sizes, int n_in,
                              void* d_out, int out_size, void* d_ws, size_t ws_size,
                              hipStream_t stream) {
    const float* input = nullptr;
    const int*   adj   = nullptr;
    const float* kW    = nullptr;
    const float* vW    = nullptr;
    for (int i = 0; i < n_in; ++i) {
        if (in_sizes[i] == 8192 * 512)            input = (const float*)d_in[i];
        else if (in_sizes[i] == 512 * 64) {
            if (!kW) kW = (const float*)d_in[i]; else vW = (const float*)d_in[i];
        } else                                    adj = (const int*)d_in[i];
    }
    float* out = (float*)d_out;

    char* ws = (char*)d_ws;
    bf16_t* khs_hi = (bf16_t*)ws;                            // 1 MB
    bf16_t* khs_lo = (bf16_t*)(ws + 1u * 1024 * 1024);       // 1 MB
    bf16_t* vhT    = (bf16_t*)(ws + 2u * 1024 * 1024);       // 1 MB
    float*  acc    = (float*)(ws + 3u * 1024 * 1024);        // ~2.2 MB
    unsigned long long* mask64 = (unsigned long long*)(ws + 6u * 1024 * 1024); // 8 MB

    zero_acc<<<(NN * ACCW + 255) / 256, 256, 0, stream>>>(acc);
    proj_kernel<<<128, 256, 0, stream>>>(input, kW, vW, khs_hi, khs_lo, vhT);
    bitpack<<<2048, 256, 0, stream>>>(adj, mask64);
    attn_kernel<<<1024, 512, 0, stream>>>((const unsigned int*)mask64, khs_hi, khs_lo, vhT, acc);
    finalize<<<(NN * 64) / 512, 512, 0, stream>>>(acc, out);
}

// Round 10
// 528.308 us; speedup vs baseline: 1.1451x; 1.1451x over previous
//
#include <hip/hip_runtime.h>
#include <math.h>

typedef __bf16 bf16_t;
typedef __bf16 bf16x8 __attribute__((ext_vector_type(8)));
typedef float f32x4 __attribute__((ext_vector_type(4)));

#define NN 8192
#define L2E 1.44269504088896340736f
#define SMAX 45.0f                    // fixed softmax shift: s-SMAX in [-75,+15], all normal fp32
#define KSCALE 0.35355339059327373f   // 1/sqrt(8); applied to khs on both sides => kh·kh/8
#define ACCW 66                       // acc row stride: 64 O cols + 1 l col + pad

// ---------------------------------------------------------------------------
// Kernel 1: projections (verified R5-R9).
// ---------------------------------------------------------------------------
__global__ __launch_bounds__(256) void proj_kernel(
    const float* __restrict__ input,
    const float* __restrict__ kW,
    const float* __restrict__ vW,
    bf16_t* __restrict__ khs_hi,
    bf16_t* __restrict__ khs_lo,
    bf16_t* __restrict__ vhT)
{
    __shared__ __align__(16) bf16_t WkH[64][136];
    __shared__ __align__(16) bf16_t WkL[64][136];
    __shared__ __align__(16) bf16_t WvH[64][136];
    __shared__ __align__(16) bf16_t WvL[64][136];

    const int tid   = threadIdx.x;
    const int wv    = tid >> 6;
    const int lane  = tid & 63;
    const int l15   = lane & 15;
    const int quad  = lane >> 4;
    const int rbase = blockIdx.x * 64 + wv * 16;

    f32x4 kacc[4] = {};
    f32x4 vacc[4] = {};

    for (int kk = 0; kk < 4; ++kk) {
        __syncthreads();
        #pragma unroll
        for (int i = 0; i < 32; ++i) {
            int idx = tid + i * 256;
            int kl  = idx >> 6;
            int n   = idx & 63;
            float wk  = kW[(kk * 128 + kl) * 64 + n];
            float wv2 = vW[(kk * 128 + kl) * 64 + n];
            bf16_t kh = (bf16_t)wk;
            bf16_t vh = (bf16_t)wv2;
            WkH[n][kl] = kh;  WkL[n][kl] = (bf16_t)(wk - (float)kh);
            WvH[n][kl] = vh;  WvL[n][kl] = (bf16_t)(wv2 - (float)vh);
        }
        __syncthreads();

        #pragma unroll
        for (int kc = 0; kc < 4; ++kc) {
            const float* ap = &input[(size_t)(rbase + l15) * 512 + kk * 128 + kc * 32 + quad * 8];
            f32x4 a0 = *(const f32x4*)ap;
            f32x4 a1 = *(const f32x4*)(ap + 4);
            bf16x8 ah, al;
            #pragma unroll
            for (int j = 0; j < 4; ++j) {
                bf16_t h0 = (bf16_t)a0[j], h1 = (bf16_t)a1[j];
                ah[j]     = h0;  al[j]     = (bf16_t)(a0[j] - (float)h0);
                ah[4 + j] = h1;  al[4 + j] = (bf16_t)(a1[j] - (float)h1);
            }
            #pragma unroll
            for (int nb = 0; nb < 4; ++nb) {
                bf16x8 bkh = *(const bf16x8*)&WkH[nb * 16 + l15][kc * 32 + quad * 8];
                bf16x8 bkl = *(const bf16x8*)&WkL[nb * 16 + l15][kc * 32 + quad * 8];
                bf16x8 bvh = *(const bf16x8*)&WvH[nb * 16 + l15][kc * 32 + quad * 8];
                bf16x8 bvl = *(const bf16x8*)&WvL[nb * 16 + l15][kc * 32 + quad * 8];
                kacc[nb] = __builtin_amdgcn_mfma_f32_16x16x32_bf16(ah, bkh, kacc[nb], 0, 0, 0);
                kacc[nb] = __builtin_amdgcn_mfma_f32_16x16x32_bf16(al, bkh, kacc[nb], 0, 0, 0);
                kacc[nb] = __builtin_amdgcn_mfma_f32_16x16x32_bf16(ah, bkl, kacc[nb], 0, 0, 0);
                vacc[nb] = __builtin_amdgcn_mfma_f32_16x16x32_bf16(ah, bvh, vacc[nb], 0, 0, 0);
                vacc[nb] = __builtin_amdgcn_mfma_f32_16x16x32_bf16(al, bvh, vacc[nb], 0, 0, 0);
                vacc[nb] = __builtin_amdgcn_mfma_f32_16x16x32_bf16(ah, bvl, vacc[nb], 0, 0, 0);
            }
        }
    }

    #pragma unroll
    for (int nb = 0; nb < 4; ++nb) {
        const int dcol = nb * 16 + l15;
        #pragma unroll
        for (int r = 0; r < 4; ++r) {
            float v  = kacc[nb][r] * KSCALE;
            bf16_t h = (bf16_t)v;
            khs_hi[(size_t)(rbase + quad * 4 + r) * 64 + dcol] = h;
            khs_lo[(size_t)(rbase + quad * 4 + r) * 64 + dcol] = (bf16_t)(v - (float)h);
        }
        union { bf16_t b[4]; uint2 u; } pk;
        #pragma unroll
        for (int r = 0; r < 4; ++r) pk.b[r] = (bf16_t)vacc[nb][r];
        *(uint2*)&vhT[(size_t)dcol * NN + rbase + quad * 4] = pk.u;
    }
}

// ---------------------------------------------------------------------------
// Kernel 1b: bitpack adj (268 MB int32) -> mask (8 MB). Pure stream.
// ---------------------------------------------------------------------------
__global__ __launch_bounds__(256) void bitpack(
    const int* __restrict__ adj, unsigned long long* __restrict__ mask64)
{
    const int gw   = (blockIdx.x * 256 + threadIdx.x) >> 6;
    const int lane = threadIdx.x & 63;
    const int* rp  = adj + (size_t)gw * NN + lane;
    unsigned long long* mp = mask64 + (size_t)gw * 128;
    #pragma unroll 8
    for (int g = 0; g < 128; ++g) {
        int v = rp[(size_t)g * 64];
        unsigned long long b = __ballot(v > 0);
        if (lane == 0) mp[g] = b;
    }
}

// ---------------------------------------------------------------------------
// Kernel 1c: repack K/V into MFMA-fragment-tiled layout so every in-loop
// attn load is lane-contiguous (base + lane*16B). One 16B chunk per thread;
// does the scatter-gather ONCE instead of every attn iteration.
//   ktile[t][f][lane]: f0/f1 = keys 32t+kperm(l15)(+0), dims q*8 / 32+q*8;
//                      f2/f3 = keys +4. kperm(m)=8*(m>>2)+(m&3).
//   vtile[t][g][lane]: vhT[16g+l15][32t + q*8 .. +8]
// ---------------------------------------------------------------------------
__global__ __launch_bounds__(256) void repack(
    const bf16_t* __restrict__ khs_hi, const bf16_t* __restrict__ vhT,
    bf16_t* __restrict__ ktile, bf16_t* __restrict__ vtile)
{
    int idx = blockIdx.x * 256 + threadIdx.x;       // 0..131071
    int c    = idx & 65535;
    int t    = c >> 8;
    int rem  = c & 255;
    int f    = rem >> 6;
    int lane = rem & 63;
    int quad = lane >> 4;
    int l15  = lane & 15;
    if (idx < 65536) {
        int kperm = ((l15 >> 2) << 3) | (l15 & 3);
        int key = 32 * t + kperm + (f >> 1) * 4;
        int dim = (f & 1) * 32 + quad * 8;
        uint4 v = *(const uint4*)(khs_hi + (size_t)key * 64 + dim);
        *(uint4*)(ktile + (size_t)t * 2048 + f * 512 + lane * 8) = v;
    } else {
        uint4 v = *(const uint4*)(vhT + (size_t)(16 * f + l15) * NN + 32 * t + quad * 8);
        *(uint4*)(vtile + (size_t)t * 2048 + f * 512 + lane * 8) = v;
    }
}

__global__ void zero_acc(float* __restrict__ acc) {
    int i = blockIdx.x * blockDim.x + threadIdx.x;
    if (i < NN * ACCW) acc[i] = 0.f;
}

// ---------------------------------------------------------------------------
// Kernel 2: transpose-free fixed-max attention (math identical to R9), all
// in-loop loads lane-contiguous 1KB from ktile/vtile. No LDS in loop.
// grid 1024 = 512 row-blocks x 2 col halves; 8 waves; 16 iters of 32 keys.
// ---------------------------------------------------------------------------
__global__ __launch_bounds__(512, 4) void attn_kernel(
    const unsigned int* __restrict__ mask,   // [8192][256] words
    const bf16_t* __restrict__ khs_hi,
    const bf16_t* __restrict__ khs_lo,
    const bf16_t* __restrict__ ktile,        // [256 tiles][4][512] bf16
    const bf16_t* __restrict__ vtile,        // [256 tiles][4][512] bf16
    float* __restrict__ acc)                 // [8192][ACCW]
{
    __shared__ __align__(16) float Msl[4 * 16 * 68];   // merge slabs (epilogue only)

    const int tid   = threadIdx.x;
    const int w     = tid >> 6;
    const int lane  = tid & 63;
    const int l15   = lane & 15;
    const int quad  = lane >> 4;
    const int rb    = blockIdx.x >> 1;
    const int ch    = blockIdx.x & 1;
    const int qbase = rb * 16;
    const int tile0 = ch * 128 + w * 16;     // this wave's first 32-key tile

    // Q fragments (B-side; n=l15=query, k=quad*8+j), hi + lo
    const bf16x8 qh0 = *(const bf16x8*)&khs_hi[(size_t)(qbase + l15) * 64 + quad * 8];
    const bf16x8 qh1 = *(const bf16x8*)&khs_hi[(size_t)(qbase + l15) * 64 + 32 + quad * 8];
    const bf16x8 ql0 = *(const bf16x8*)&khs_lo[(size_t)(qbase + l15) * 64 + quad * 8];
    const bf16x8 ql1 = *(const bf16x8*)&khs_lo[(size_t)(qbase + l15) * 64 + 32 + quad * 8];

    bf16x8 ones;
    #pragma unroll
    for (int j = 0; j < 8; ++j) ones[j] = (bf16_t)1.0f;

    // per-lane mask words for row qbase+l15
    const uint4* mrow = (const uint4*)(mask + (size_t)(qbase + l15) * 256 + tile0);

    f32x4 o0 = {}, o1 = {}, o2 = {}, o3 = {}, o4 = {};

    const bf16_t* kbase = ktile + (size_t)tile0 * 2048 + lane * 8;
    const bf16_t* vbase = vtile + (size_t)tile0 * 2048 + lane * 8;

    for (int t0 = 0; t0 < 4; ++t0) {
        uint4 mw4 = mrow[t0];
        #pragma unroll
        for (int u = 0; u < 4; ++u) {
            const int t = t0 * 4 + u;
            const unsigned int word = (&mw4.x)[u];
            const bf16_t* kp = kbase + (size_t)t * 2048;
            const bf16_t* vp = vbase + (size_t)t * 2048;

            // lane-contiguous fragment loads (each: wave covers 1KB)
            bf16x8 a00 = *(const bf16x8*)(kp);
            bf16x8 a01 = *(const bf16x8*)(kp + 512);
            bf16x8 a10 = *(const bf16x8*)(kp + 1024);
            bf16x8 a11 = *(const bf16x8*)(kp + 1536);
            bf16x8 bv0 = *(const bf16x8*)(vp);
            bf16x8 bv1 = *(const bf16x8*)(vp + 512);
            bf16x8 bv2 = *(const bf16x8*)(vp + 1024);
            bf16x8 bv3 = *(const bf16x8*)(vp + 1536);

            // S^T tiles: D[m=key-slot][n=query]
            f32x4 zz = {};
            f32x4 c0 = __builtin_amdgcn_mfma_f32_16x16x32_bf16(a00, qh0, zz, 0, 0, 0);
            c0 = __builtin_amdgcn_mfma_f32_16x16x32_bf16(a01, qh1, c0, 0, 0, 0);
            c0 = __builtin_amdgcn_mfma_f32_16x16x32_bf16(a00, ql0, c0, 0, 0, 0);
            c0 = __builtin_amdgcn_mfma_f32_16x16x32_bf16(a01, ql1, c0, 0, 0, 0);
            f32x4 c1 = __builtin_amdgcn_mfma_f32_16x16x32_bf16(a10, qh0, zz, 0, 0, 0);
            c1 = __builtin_amdgcn_mfma_f32_16x16x32_bf16(a11, qh1, c1, 0, 0, 0);
            c1 = __builtin_amdgcn_mfma_f32_16x16x32_bf16(a10, ql0, c1, 0, 0, 0);
            c1 = __builtin_amdgcn_mfma_f32_16x16x32_bf16(a11, ql1, c1, 0, 0, 0);

            // p = maskbit ? exp(s - SMAX) : 0 ; c0[r] -> key 8*quad+r, c1[r] -> +4
            bf16x8 pa;
            #pragma unroll
            for (int r = 0; r < 4; ++r) {
                float p0 = ((word >> (8 * quad + r)) & 1u)
                             ? __builtin_amdgcn_exp2f((c0[r] - SMAX) * L2E) : 0.f;
                float p1 = ((word >> (8 * quad + 4 + r)) & 1u)
                             ? __builtin_amdgcn_exp2f((c1[r] - SMAX) * L2E) : 0.f;
                pa[r]     = (bf16_t)p0;
                pa[4 + r] = (bf16_t)p1;
            }

            // PV + l, all in registers
            o0 = __builtin_amdgcn_mfma_f32_16x16x32_bf16(pa, bv0, o0, 0, 0, 0);
            o1 = __builtin_amdgcn_mfma_f32_16x16x32_bf16(pa, bv1, o1, 0, 0, 0);
            o2 = __builtin_amdgcn_mfma_f32_16x16x32_bf16(pa, bv2, o2, 0, 0, 0);
            o3 = __builtin_amdgcn_mfma_f32_16x16x32_bf16(pa, bv3, o3, 0, 0, 0);
            o4 = __builtin_amdgcn_mfma_f32_16x16x32_bf16(pa, ones, o4, 0, 0, 0);
        }
    }

    // ---- sum-tree merge of the 8 waves (epilogue only) ----
    float* M = Msl;
    #pragma unroll
    for (int s = 4; s >= 1; s >>= 1) {
        __syncthreads();
        if (w >= s && w < 2 * s) {
            float* base = M + (w - s) * 16 * 68;
            #pragma unroll
            for (int r = 0; r < 4; ++r) {
                const int row = quad * 4 + r;
                base[row * 68 + l15]      = o0[r];
                base[row * 68 + 16 + l15] = o1[r];
                base[row * 68 + 32 + l15] = o2[r];
                base[row * 68 + 48 + l15] = o3[r];
                if (l15 == 0) base[row * 68 + 64] = o4[r];
            }
        }
        __syncthreads();
        if (w < s) {
            float* base = M + w * 16 * 68;
            #pragma unroll
            for (int r = 0; r < 4; ++r) {
                const int row = quad * 4 + r;
                o0[r] += base[row * 68 + l15];
                o1[r] += base[row * 68 + 16 + l15];
                o2[r] += base[row * 68 + 32 + l15];
                o3[r] += base[row * 68 + 48 + l15];
                o4[r] += base[row * 68 + 64];
            }
        }
    }

    if (w == 0) {
        #pragma unroll
        for (int r = 0; r < 4; ++r) {
            const size_t row = (size_t)qbase + quad * 4 + r;
            atomicAdd(&acc[row * ACCW + l15],      o0[r]);
            atomicAdd(&acc[row * ACCW + 16 + l15], o1[r]);
            atomicAdd(&acc[row * ACCW + 32 + l15], o2[r]);
            atomicAdd(&acc[row * ACCW + 48 + l15], o3[r]);
            if (l15 == 0) atomicAdd(&acc[row * ACCW + 64], o4[r]);
        }
    }
}

__global__ void finalize(const float* __restrict__ acc, float* __restrict__ out) {
    int i = blockIdx.x * blockDim.x + threadIdx.x;
    int row = i >> 6, d = i & 63;
    float l = acc[(size_t)row * ACCW + 64];
    float v = acc[(size_t)row * ACCW + d] / (l > 0.f ? l : 1.f);
    out[i] = v > 0.f ? v : expm1f(v);
}

// ---------------------------------------------------------------------------
extern "C" void kernel_launch(void* const* d_in, const int* in_sizes, int n_in,
                              void* d_out, int out_size, void* d_ws, size_t ws_size,
                              hipStream_t stream) {
    const float* input = nullptr;
    const int*   adj   = nullptr;
    const float* kW    = nullptr;
    const float* vW    = nullptr;
    for (int i = 0; i < n_in; ++i) {
        if (in_sizes[i] == 8192 * 512)            input = (const float*)d_in[i];
        else if (in_sizes[i] == 512 * 64) {
            if (!kW) kW = (const float*)d_in[i]; else vW = (const float*)d_in[i];
        } else                                    adj = (const int*)d_in[i];
    }
    float* out = (float*)d_out;

    char* ws = (char*)d_ws;
    bf16_t* khs_hi = (bf16_t*)ws;                            // 1 MB
    bf16_t* khs_lo = (bf16_t*)(ws + 1u * 1024 * 1024);       // 1 MB
    bf16_t* vhT    = (bf16_t*)(ws + 2u * 1024 * 1024);       // 1 MB
    float*  acc    = (float*)(ws + 3u * 1024 * 1024);        // ~2.2 MB
    unsigned long long* mask64 = (unsigned long long*)(ws + 6u * 1024 * 1024); // 8 MB
    bf16_t* ktile  = (bf16_t*)(ws + 14u * 1024 * 1024);      // 1 MB
    bf16_t* vtile  = (bf16_t*)(ws + 15u * 1024 * 1024);      // 1 MB

    zero_acc<<<(NN * ACCW + 255) / 256, 256, 0, stream>>>(acc);
    proj_kernel<<<128, 256, 0, stream>>>(input, kW, vW, khs_hi, khs_lo, vhT);
    bitpack<<<2048, 256, 0, stream>>>(adj, mask64);
    repack<<<512, 256, 0, stream>>>(khs_hi, vhT, ktile, vtile);
    attn_kernel<<<1024, 512, 0, stream>>>((const unsigned int*)mask64, khs_hi, khs_lo,
                                          ktile, vtile, acc);
    finalize<<<(NN * 64) / 512, 512, 0, stream>>>(acc, out);
}